// Round 9
// baseline (856.462 us; speedup 1.0000x reference)
//
#include <hip/hip_runtime.h>
#include <hip/hip_bf16.h>

// LRUModel r9: launch-count reduction (54 -> 43).
//  - k_bngelu eliminated: gelu(bn(y))+x fused into consumer A-staging
//    (gemm l=1, u-drive gemm, logits). h1 written back to separate HB buffer
//    by blockIdx.y==0 only (no race with sibling block reading old h).
//  - k_embed eliminated: blk0 scan computes u = Wi0[x]+bi0 in epilogue.
//  - Buffers: U, HA(scan/corr), HB(h1), Y0(y_l0), Y1(y_l1) fp16 slabs.
// B=8,S=2048,D=256,V=6, 4 blocks of [linear-RNN scan -> 2x(Linear+BN+gelu+res)]

#define DD 256
#define NTOT 16384
#define L1C 16
#define EPSV 1e-5f

typedef unsigned short ushort_t;
typedef __attribute__((ext_vector_type(8))) unsigned short ushort8;
typedef __attribute__((ext_vector_type(8))) _Float16 f16x8;
typedef __attribute__((ext_vector_type(4))) float f32x4;

// ws layout (float offsets)
#define OFF_U     0L          // fp16 16384x256
#define OFF_HA    2097152L    // fp16 scan/corr state
#define OFF_HB    4194304L    // fp16 h1 writeback
#define OFF_Y0    6291456L    // fp16 y(l=0)
#define OFF_Y1    8388608L    // fp16 y(l=1)
#define OFF_E1    10485760L   // f32 1024*256
#define OFF_EE1   10747904L   // f32 1024*256
#define OFF_E2    11010048L   // f32 64*256
#define OFF_T2    11026432L   // f32 64*256
#define OFF_ST    11042816L   // f32 8*512
#define OFF_SLABF 11046912L   // f32 2*16*65536 (Wh^1..Wh^16)
#define OFF_P256F 13144064L   // f32 2*65536
#define OFF_TA    13275136L   // f32 2*65536
#define OFF_TB    13406208L   // f32 2*65536
#define OFF_SLABT 13537280L   // fp16 2*16*65536
#define OFF_WTT   14585856L   // fp16 5*65536 (Wi1,m0W0,m0W1,m1W0,m1W1 T)

__device__ __forceinline__ ushort_t hc(float f) {
  return __builtin_bit_cast(ushort_t, (_Float16)f);
}
__device__ __forceinline__ float hf(ushort_t u) {
  return (float)__builtin_bit_cast(_Float16, u);
}
__device__ __forceinline__ f16x8 ldsf16(const ushort_t* p, int idx) {
  return __builtin_bit_cast(f16x8, *(const ushort8*)(p + idx));
}
__device__ __forceinline__ f32x4 mfma16h(f16x8 a, f16x8 b, f32x4 c) {
  return __builtin_amdgcn_mfma_f32_16x16x32_f16(a, b, c, 0, 0, 0);
}
__device__ __forceinline__ float gelu_fast(float x) {
  const float z = 0.7978845608028654f * (x + 0.044715f * x * x * x);
  return x / (1.f + __expf(-2.f * z));
}

// ---------------- f32 64x64-tile GEMM (power-slab construction only) ---------
__device__ __forceinline__ void mm_tile(const float* __restrict__ A,
                                        const float* __restrict__ W,
                                        float* __restrict__ C) {
  __shared__ float As[16][68];
  __shared__ float Bs[16][68];
  const int tid = threadIdx.x;
  const int tx = tid & 15;
  const int ty = tid >> 4;
  const int bm = blockIdx.x * 64;
  const int bn = blockIdx.y * 64;
  float acc[4][4] = {};
  for (int k0 = 0; k0 < 256; k0 += 16) {
    {
      const int m = tid >> 2, ks = (tid & 3) * 4;
      const float4 av = *(const float4*)(A + (bm + m) * 256 + k0 + ks);
      As[ks + 0][m] = av.x; As[ks + 1][m] = av.y;
      As[ks + 2][m] = av.z; As[ks + 3][m] = av.w;
    }
    {
      const int kk = tid >> 4, n4 = (tid & 15) * 4;
      const float4 wv = *(const float4*)(W + (k0 + kk) * 256 + bn + n4);
      Bs[kk][n4 + 0] = wv.x; Bs[kk][n4 + 1] = wv.y;
      Bs[kk][n4 + 2] = wv.z; Bs[kk][n4 + 3] = wv.w;
    }
    __syncthreads();
#pragma unroll
    for (int kk = 0; kk < 16; ++kk) {
      const float a0 = As[kk][ty * 4 + 0];
      const float a1 = As[kk][ty * 4 + 1];
      const float a2 = As[kk][ty * 4 + 2];
      const float a3 = As[kk][ty * 4 + 3];
      const float4 b = *(const float4*)(&Bs[kk][tx * 4]);
      acc[0][0] = fmaf(a0, b.x, acc[0][0]); acc[0][1] = fmaf(a0, b.y, acc[0][1]);
      acc[0][2] = fmaf(a0, b.z, acc[0][2]); acc[0][3] = fmaf(a0, b.w, acc[0][3]);
      acc[1][0] = fmaf(a1, b.x, acc[1][0]); acc[1][1] = fmaf(a1, b.y, acc[1][1]);
      acc[1][2] = fmaf(a1, b.z, acc[1][2]); acc[1][3] = fmaf(a1, b.w, acc[1][3]);
      acc[2][0] = fmaf(a2, b.x, acc[2][0]); acc[2][1] = fmaf(a2, b.y, acc[2][1]);
      acc[2][2] = fmaf(a2, b.z, acc[2][2]); acc[2][3] = fmaf(a2, b.w, acc[2][3]);
      acc[3][0] = fmaf(a3, b.x, acc[3][0]); acc[3][1] = fmaf(a3, b.y, acc[3][1]);
      acc[3][2] = fmaf(a3, b.z, acc[3][2]); acc[3][3] = fmaf(a3, b.w, acc[3][3]);
    }
    __syncthreads();
  }
#pragma unroll
  for (int i = 0; i < 4; ++i) {
    float4 o;
    o.x = acc[i][0]; o.y = acc[i][1]; o.z = acc[i][2]; o.w = acc[i][3];
    *(float4*)(C + (bm + ty * 4 + i) * 256 + bn + tx * 4) = o;
  }
}

__global__ __launch_bounds__(256, 4) void k_powmm(const float* __restrict__ A,
                                                  const float* __restrict__ B,
                                                  float* __restrict__ C,
                                                  long sA, long sB, long sC, int per) {
  const int z = blockIdx.z;
  const int set = z / per, i = z % per;
  mm_tile(A + set * sA + (long)i * 65536, B + set * sB, C + set * sC + (long)i * 65536);
}

__global__ void k_copy2(const float* __restrict__ a, const float* __restrict__ b,
                        float* __restrict__ c0, float* __restrict__ c1) {
  const int i = (blockIdx.x * 256 + threadIdx.x) * 4;
  *(float4*)(c0 + i) = *(const float4*)(a + i);
  *(float4*)(c1 + i) = *(const float4*)(b + i);
}

// transpose+cast f32[256][256] -> fp16 out[n][k]; grid (16 tiles, 37 mats)
__global__ __launch_bounds__(256, 2) void k_castT(const float* __restrict__ slabF,
                                                  const float* __restrict__ Wi1,
                                                  const float* __restrict__ m0W,
                                                  const float* __restrict__ m1W,
                                                  ushort_t* __restrict__ slabT,
                                                  ushort_t* __restrict__ WtT) {
  const int mat = blockIdx.y;
  const float* src;
  ushort_t* dst;
  if (mat < 32)      { src = slabF + (long)mat * 65536;        dst = slabT + (long)mat * 65536; }
  else if (mat == 32){ src = Wi1;                              dst = WtT; }
  else if (mat < 35) { src = m0W + (long)(mat - 33) * 65536;   dst = WtT + (long)(mat - 32) * 65536; }
  else               { src = m1W + (long)(mat - 35) * 65536;   dst = WtT + (long)(mat - 32) * 65536; }
  const int rt = blockIdx.x >> 2, ct = blockIdx.x & 3;
  __shared__ float T[64][65];
  const int tid = threadIdx.x;
  {
    const int r = tid >> 2, cs = (tid & 3) * 16;
#pragma unroll
    for (int i = 0; i < 4; ++i) {
      const float4 v = *(const float4*)(src + (rt * 64 + r) * 256 + ct * 64 + cs + i * 4);
      T[r][cs + i * 4 + 0] = v.x; T[r][cs + i * 4 + 1] = v.y;
      T[r][cs + i * 4 + 2] = v.z; T[r][cs + i * 4 + 3] = v.w;
    }
  }
  __syncthreads();
  const int on = tid >> 2, ks = (tid & 3) * 16;
  ushort8 p0, p1;
#pragma unroll
  for (int i = 0; i < 8; ++i) p0[i] = hc(T[ks + i][on]);
#pragma unroll
  for (int i = 0; i < 8; ++i) p1[i] = hc(T[ks + 8 + i][on]);
  ushort_t* d = dst + (ct * 64 + on) * 256 + rt * 64 + ks;
  *(ushort8*)d = p0;
  *(ushort8*)(d + 8) = p1;
}

// ---------------- MFMA pass-1 scan; XEMB: u computed from embedding ----------
template <int XEMB>
__global__ __launch_bounds__(256, 1) void k_scan_mfma(const ushort_t* __restrict__ u,
                                                      const int* __restrict__ xidx,
                                                      const float* __restrict__ Wi,
                                                      const float* __restrict__ bi,
                                                      const ushort_t* __restrict__ Wt,
                                                      ushort_t* __restrict__ H,
                                                      float* __restrict__ E1) {
  __shared__ __align__(16) ushort_t hs[2][16 * 256];
  const int tid = threadIdx.x, lane = tid & 63, wave = tid >> 6;
  const int c0 = blockIdx.x * 16;
  const int arow = lane & 15;
  const int kgrp = lane >> 4;

  f16x8 bfrag[4][8];
#pragma unroll
  for (int nt = 0; nt < 4; ++nt) {
    const int col = wave * 64 + nt * 16 + arow;
#pragma unroll
    for (int kt = 0; kt < 8; ++kt) {
      const ushort8 p = *(const ushort8*)(Wt + col * 256 + kt * 32 + kgrp * 8);
      bfrag[nt][kt] = __builtin_bit_cast(f16x8, p);
    }
  }
  {
    ushort8 z;
#pragma unroll
    for (int q = 0; q < 8; ++q) z[q] = 0;
    *(ushort8*)&hs[0][tid * 8] = z;
    *(ushort8*)&hs[0][2048 + tid * 8] = z;
  }
  __syncthreads();

  int p = 0;
  for (int t = 0; t < L1C; ++t) {
    f16x8 afrag[8];
#pragma unroll
    for (int kt = 0; kt < 8; ++kt) {
      const int idx = arow * 256 + kt * 32 + kgrp * 8;
      afrag[kt] = ldsf16(hs[p], idx ^ ((arow & 7) << 3));
    }
#pragma unroll
    for (int nt = 0; nt < 4; ++nt) {
      f32x4 acc = {0.f, 0.f, 0.f, 0.f};
#pragma unroll
      for (int kt = 0; kt < 8; ++kt) acc = mfma16h(afrag[kt], bfrag[nt][kt], acc);
      const int col = wave * 64 + nt * 16 + arow;
#pragma unroll
      for (int i = 0; i < 4; ++i) {
        const int m = kgrp * 4 + i;
        const long grow = (long)(c0 + m) * L1C + t;
        float uval;
        if (XEMB) {
          const int xi = xidx[grow];
          uval = Wi[xi * 256 + col] + bi[col];
        } else {
          uval = hf(u[grow * 256 + col]);
        }
        const float v = acc[i] + uval;
        const ushort_t v16 = hc(v);
        H[grow * 256 + col] = v16;
        const int idx = m * 256 + col;
        hs[p ^ 1][idx ^ ((m & 7) << 3)] = v16;
        if (t == L1C - 1) E1[(long)(c0 + m) * 256 + col] = v;
      }
    }
    __syncthreads();
    p ^= 1;
  }
}

// ---------------- f32 sequential chunk scan (small levels only) --------------
__global__ __launch_bounds__(512, 2) void k_scan(const float* __restrict__ u,
                                                 const float* __restrict__ W,
                                                 const float* __restrict__ Einit,
                                                 float* __restrict__ out_full,
                                                 float* __restrict__ out_ends,
                                                 int steps, int cper) {
  const int d = threadIdx.x & 255;
  const int half = threadIdx.x >> 8;
  const long r0 = (long)blockIdx.x * 2;
  __shared__ __align__(16) float hbuf[2][DD];
  __shared__ __align__(16) float psum[2][DD];

  float w[128];
  {
    const float* Wc = W + (long)(half * 128) * DD + d;
#pragma unroll
    for (int i = 0; i < 128; ++i) w[i] = Wc[(long)i * DD];
  }

  if (half == 0) {
#pragma unroll
    for (int g = 0; g < 2; ++g) {
      const long r = r0 + g;
      float hv = 0.f;
      if (Einit != nullptr && (int)(r % cper) != 0) hv = Einit[(r - 1) * DD + d];
      hbuf[g][d] = hv;
    }
  }
  __syncthreads();

  const float* __restrict__ ur0 = u + r0 * steps * DD + d;
  const float* __restrict__ ur1 = ur0 + (long)steps * DD;
  float* of0 = out_full ? out_full + r0 * steps * DD + d : nullptr;
  float* of1 = of0 ? of0 + (long)steps * DD : nullptr;
  const int e0 = half * 128;

  for (int t = 0; t < steps; ++t) {
    float uv0 = 0.f, uv1 = 0.f;
    if (half == 0) { uv0 = ur0[(long)t * DD]; uv1 = ur1[(long)t * DD]; }
    float a00 = 0.f, a01 = 0.f, a10 = 0.f, a11 = 0.f;
    const float4* hb0 = (const float4*)(&hbuf[0][e0]);
    const float4* hb1 = (const float4*)(&hbuf[1][e0]);
#pragma unroll
    for (int i = 0; i < 32; ++i) {
      const float4 h0 = hb0[i];
      const float4 h1 = hb1[i];
      a00 = fmaf(h0.x, w[4 * i + 0], a00);
      a01 = fmaf(h0.y, w[4 * i + 1], a01);
      a00 = fmaf(h0.z, w[4 * i + 2], a00);
      a01 = fmaf(h0.w, w[4 * i + 3], a01);
      a10 = fmaf(h1.x, w[4 * i + 0], a10);
      a11 = fmaf(h1.y, w[4 * i + 1], a11);
      a10 = fmaf(h1.z, w[4 * i + 2], a10);
      a11 = fmaf(h1.w, w[4 * i + 3], a11);
    }
    const float p0 = a00 + a01;
    const float p1 = a10 + a11;
    __syncthreads();
    if (half == 1) { psum[0][d] = p0; psum[1][d] = p1; }
    __syncthreads();
    if (half == 0) {
      const float n0 = p0 + psum[0][d] + uv0;
      const float n1 = p1 + psum[1][d] + uv1;
      hbuf[0][d] = n0; hbuf[1][d] = n1;
      if (of0) { of0[(long)t * DD] = n0; of1[(long)t * DD] = n1; }
    }
    __syncthreads();
  }
  if (out_ends != nullptr && half == 0) {
    out_ends[r0 * DD + d] = hbuf[0][d];
    out_ends[(r0 + 1) * DD + d] = hbuf[1][d];
  }
}

// ---------------- fp16 MFMA GEMM with optional fused bn+gelu+res staging -----
// FUSE: A = gelu(bn(Ay;stP,scP,biP)) + Ax, optionally written back to hwb
// (blockIdx.y==0 only). STATS: per-column sum/sumsq of C into stats (atomics).
template <int STATS, int FUSE>
__global__ __launch_bounds__(256, 2) void k_gemm(const ushort_t* __restrict__ Ay,
                                                 const ushort_t* __restrict__ Ax,
                                                 const float* __restrict__ stP,
                                                 const float* __restrict__ scP,
                                                 const float* __restrict__ biP,
                                                 const ushort_t* __restrict__ BT,
                                                 const float* __restrict__ bias,
                                                 ushort_t* __restrict__ C,
                                                 float* __restrict__ stats,
                                                 ushort_t* __restrict__ hwb) {
  __shared__ __align__(16) ushort_t As[128 * 64];
  __shared__ __align__(16) ushort_t Bs[128 * 64];
  const int tid = threadIdx.x;
  const int lane = tid & 63;
  const int wave = tid >> 6;
  const int wr = wave >> 1, wc = wave & 1;
  const long m0 = (long)blockIdx.x * 128;
  const int n0 = blockIdx.y * 128;
  f32x4 acc[4][4];
#pragma unroll
  for (int i = 0; i < 4; ++i)
#pragma unroll
    for (int jn = 0; jn < 4; ++jn) acc[i][jn] = {0.f, 0.f, 0.f, 0.f};

  const int sr = tid >> 3;
  const int sk = (tid & 7) * 8;
#pragma unroll 1
  for (int kt = 0; kt < 4; ++kt) {
    const int kg = kt * 64;
    float mu8[8], al8[8], be8[8];
    if (FUSE) {
#pragma unroll
      for (int q = 0; q < 8; ++q) {
        const int col = kg + sk + q;
        const float mu = stP[col] * (1.f / NTOT);
        const float var = stP[256 + col] * (1.f / NTOT) - mu * mu;
        mu8[q] = mu;
        al8[q] = scP[col] * rsqrtf(var + EPSV);
        be8[q] = biP[col];
      }
    }
#pragma unroll
    for (int it = 0; it < 4; ++it) {
      const int r = sr + it * 32;
      const long row = m0 + r;
      ushort8 p = *(const ushort8*)(Ay + row * 256 + kg + sk);
      if (FUSE) {
        const ushort8 px = *(const ushort8*)(Ax + row * 256 + kg + sk);
#pragma unroll
        for (int q = 0; q < 8; ++q) {
          const float hv = gelu_fast((hf(p[q]) - mu8[q]) * al8[q] + be8[q]) + hf(px[q]);
          p[q] = hc(hv);
        }
        if (hwb != nullptr && blockIdx.y == 0)
          *(ushort8*)(hwb + row * 256 + kg + sk) = p;
      }
      *(ushort8*)&As[(r * 64 + sk) ^ ((r & 7) << 3)] = p;
    }
#pragma unroll
    for (int it = 0; it < 4; ++it) {
      const int n = sr + it * 32;
      const ushort8 p = *(const ushort8*)(BT + (long)(n0 + n) * 256 + kg + sk);
      *(ushort8*)&Bs[(n * 64 + sk) ^ ((n & 7) << 3)] = p;
    }
    __syncthreads();
#pragma unroll
    for (int kk = 0; kk < 2; ++kk) {
      const int kb = kk * 32 + (lane >> 4) * 8;
      f16x8 af[4], bfr[4];
#pragma unroll
      for (int m = 0; m < 4; ++m) {
        const int row = wr * 64 + m * 16 + (lane & 15);
        af[m] = ldsf16(As, (row * 64 + kb) ^ ((row & 7) << 3));
      }
#pragma unroll
      for (int n = 0; n < 4; ++n) {
        const int col = wc * 64 + n * 16 + (lane & 15);
        bfr[n] = ldsf16(Bs, (col * 64 + kb) ^ ((col & 7) << 3));
      }
#pragma unroll
      for (int m = 0; m < 4; ++m)
#pragma unroll
        for (int n = 0; n < 4; ++n)
          acc[m][n] = mfma16h(af[m], bfr[n], acc[m][n]);
    }
    __syncthreads();
  }
  const int crow = (lane >> 4) * 4;
  const int ccol = lane & 15;
#pragma unroll
  for (int n = 0; n < 4; ++n) {
    const int col = n0 + wc * 64 + n * 16 + ccol;
    const float bv = bias[col];
    float cs = 0.f, cq = 0.f;
#pragma unroll
    for (int m = 0; m < 4; ++m) {
      const long rbase = m0 + wr * 64 + m * 16 + crow;
#pragma unroll
      for (int i = 0; i < 4; ++i) {
        const float v = acc[m][n][i] + bv;
        C[(rbase + i) * 256 + col] = hc(v);
        if (STATS) { cs += v; cq = fmaf(v, v, cq); }
      }
    }
    if (STATS) {
      cs += __shfl_xor(cs, 16); cq += __shfl_xor(cq, 16);
      cs += __shfl_xor(cs, 32); cq += __shfl_xor(cq, 32);
      if ((lane >> 4) == 0) {
        atomicAdd(&stats[col], cs);
        atomicAdd(&stats[256 + col], cq);
      }
    }
  }
}

// ---------------- correction: H[c*16+j] += Init[c] @ Wh^{j+1} (fp16 RMW) -----
__global__ __launch_bounds__(256, 2) void k_corr(const float* __restrict__ EE1,
                                                 const ushort_t* __restrict__ slabT,
                                                 ushort_t* __restrict__ H) {
  __shared__ __align__(16) ushort_t As[128 * 64];
  __shared__ __align__(16) ushort_t Bs[128 * 64];
  const int tid = threadIdx.x;
  const int lane = tid & 63;
  const int wave = tid >> 6;
  const int wr = wave >> 1, wc = wave & 1;
  const int m0 = blockIdx.x * 128;
  const int n0 = blockIdx.y * 128;
  const int j = blockIdx.z;
  const ushort_t* BT = slabT + (long)j * 65536;
  f32x4 acc[4][4];
#pragma unroll
  for (int i = 0; i < 4; ++i)
#pragma unroll
    for (int jn = 0; jn < 4; ++jn) acc[i][jn] = {0.f, 0.f, 0.f, 0.f};

  const int sr = tid >> 3;
  const int sk = (tid & 7) * 8;
#pragma unroll 1
  for (int kt = 0; kt < 4; ++kt) {
    const int kg = kt * 64;
#pragma unroll
    for (int it = 0; it < 4; ++it) {
      const int c = m0 + sr + it * 32;
      ushort8 p;
#pragma unroll
      for (int q = 0; q < 8; ++q) p[q] = 0;
      if ((c & 127) != 0) {
        const float* src = EE1 + (long)(c - 1) * 256 + kg + sk;
        const float4 f0 = *(const float4*)src;
        const float4 f1 = *(const float4*)(src + 4);
        p[0] = hc(f0.x); p[1] = hc(f0.y); p[2] = hc(f0.z); p[3] = hc(f0.w);
        p[4] = hc(f1.x); p[5] = hc(f1.y); p[6] = hc(f1.z); p[7] = hc(f1.w);
      }
      const int r = sr + it * 32;
      *(ushort8*)&As[(r * 64 + sk) ^ ((r & 7) << 3)] = p;
    }
#pragma unroll
    for (int it = 0; it < 4; ++it) {
      const int n = sr + it * 32;
      const ushort8 p = *(const ushort8*)(BT + (long)(n0 + n) * 256 + kg + sk);
      *(ushort8*)&Bs[(n * 64 + sk) ^ ((n & 7) << 3)] = p;
    }
    __syncthreads();
#pragma unroll
    for (int kk = 0; kk < 2; ++kk) {
      const int kb = kk * 32 + (lane >> 4) * 8;
      f16x8 af[4], bfr[4];
#pragma unroll
      for (int m = 0; m < 4; ++m) {
        const int row = wr * 64 + m * 16 + (lane & 15);
        af[m] = ldsf16(As, (row * 64 + kb) ^ ((row & 7) << 3));
      }
#pragma unroll
      for (int n = 0; n < 4; ++n) {
        const int col = wc * 64 + n * 16 + (lane & 15);
        bfr[n] = ldsf16(Bs, (col * 64 + kb) ^ ((col & 7) << 3));
      }
#pragma unroll
      for (int m = 0; m < 4; ++m)
#pragma unroll
        for (int n = 0; n < 4; ++n)
          acc[m][n] = mfma16h(af[m], bfr[n], acc[m][n]);
    }
    __syncthreads();
  }
  const int crow = (lane >> 4) * 4;
  const int ccol = lane & 15;
#pragma unroll
  for (int m = 0; m < 4; ++m) {
    const int cbase = m0 + wr * 64 + m * 16 + crow;
#pragma unroll
    for (int n = 0; n < 4; ++n) {
      const int col = n0 + wc * 64 + n * 16 + ccol;
#pragma unroll
      for (int i = 0; i < 4; ++i) {
        ushort_t* p = H + ((long)(cbase + i) * 16 + j) * 256 + col;
        *p = hc(hf(*p) + acc[m][n][i]);
      }
    }
  }
}

// ---------------- logits via MFMA; fused h_final = gelu(bn(y1))+h1 -----------
__global__ __launch_bounds__(256, 2) void k_logits(const ushort_t* __restrict__ Ay,
                                                   const ushort_t* __restrict__ Ax,
                                                   const float* __restrict__ stP,
                                                   const float* __restrict__ scP,
                                                   const float* __restrict__ biP,
                                                   const float* __restrict__ Wr,
                                                   const float* __restrict__ br,
                                                   float* __restrict__ out) {
  __shared__ __align__(16) ushort_t Hs[64 * 256];
  __shared__ __align__(16) ushort_t Ws[16 * 256];
  const int tid = threadIdx.x, lane = tid & 63, wave = tid >> 6;
  const long r0 = (long)blockIdx.x * 64;
  const int hr = tid >> 2;
#pragma unroll
  for (int it = 0; it < 8; ++it) {
    const int kq = (tid & 3) * 8 + it * 32;
    ushort8 p = *(const ushort8*)(Ay + (r0 + hr) * 256 + kq);
    const ushort8 px = *(const ushort8*)(Ax + (r0 + hr) * 256 + kq);
#pragma unroll
    for (int q = 0; q < 8; ++q) {
      const int col = kq + q;
      const float mu = stP[col] * (1.f / NTOT);
      const float var = stP[256 + col] * (1.f / NTOT) - mu * mu;
      const float a = scP[col] * rsqrtf(var + EPSV);
      p[q] = hc(gelu_fast((hf(p[q]) - mu) * a + biP[col]) + hf(px[q]));
    }
    *(ushort8*)&Hs[(hr * 256 + kq) ^ ((hr & 7) << 3)] = p;
  }
  {
    float w6[6];
#pragma unroll
    for (int v = 0; v < 6; ++v) w6[v] = Wr[tid * 6 + v];
#pragma unroll
    for (int v = 0; v < 16; ++v)
      Ws[(v * 256 + tid) ^ ((v & 7) << 3)] = (v < 6) ? hc(w6[v]) : (ushort_t)0;
  }
  __syncthreads();
  f32x4 acc = {0.f, 0.f, 0.f, 0.f};
  const int arow = wave * 16 + (lane & 15);
  const int vcol = lane & 15;
#pragma unroll
  for (int kk = 0; kk < 8; ++kk) {
    const int kb = kk * 32 + (lane >> 4) * 8;
    const f16x8 a = ldsf16(Hs, (arow * 256 + kb) ^ ((arow & 7) << 3));
    const f16x8 b = ldsf16(Ws, (vcol * 256 + kb) ^ ((vcol & 7) << 3));
    acc = mfma16h(a, b, acc);
  }
  if (vcol < 6) {
    const float bv = br[vcol];
    const long rb = r0 + wave * 16 + (lane >> 4) * 4;
#pragma unroll
    for (int i = 0; i < 4; ++i) out[(rb + i) * 6 + vcol] = acc[i] + bv;
  }
}

extern "C" void kernel_launch(void* const* d_in, const int* in_sizes, int n_in,
                              void* d_out, int out_size, void* d_ws, size_t ws_size,
                              hipStream_t stream) {
  const int* x = (const int*)d_in[0];
  const float* Wi0 = (const float*)d_in[1];
  const float* bi0 = (const float*)d_in[2];
  const float* Wh0 = (const float*)d_in[3];
  const float* m0W = (const float*)d_in[4];
  const float* m0b = (const float*)d_in[5];
  const float* m0s = (const float*)d_in[6];
  const float* m0bi = (const float*)d_in[7];
  const float* Wi1 = (const float*)d_in[8];
  const float* bi1 = (const float*)d_in[9];
  const float* Wh1 = (const float*)d_in[10];
  const float* m1W = (const float*)d_in[11];
  const float* m1b = (const float*)d_in[12];
  const float* m1s = (const float*)d_in[13];
  const float* m1bi = (const float*)d_in[14];
  const float* Wr = (const float*)d_in[15];
  const float* br = (const float*)d_in[16];

  float* ws = (float*)d_ws;
  ushort_t* U = (ushort_t*)(ws + OFF_U);
  ushort_t* HA = (ushort_t*)(ws + OFF_HA);
  ushort_t* HB = (ushort_t*)(ws + OFF_HB);
  ushort_t* Y0 = (ushort_t*)(ws + OFF_Y0);
  ushort_t* Y1 = (ushort_t*)(ws + OFF_Y1);
  float* e1 = ws + OFF_E1;
  float* ee1 = ws + OFF_EE1;
  float* e2 = ws + OFF_E2;
  float* t2 = ws + OFF_T2;
  float* stats = ws + OFF_ST;
  float* slabF = ws + OFF_SLABF;
  float* P256F = ws + OFF_P256F;
  float* tA = ws + OFF_TA;
  float* tB = ws + OFF_TB;
  ushort_t* slabT = (ushort_t*)(ws + OFF_SLABT);
  ushort_t* WtT = (ushort_t*)(ws + OFF_WTT);
  const long SS = 16L * 65536;

  // power slab: slab[i] = Wh^{i+1}, i=0..15, both param sets; P256 = Wh^256
  k_copy2<<<64, 256, 0, stream>>>(Wh0, Wh1, slabF, slabF + SS);
  k_powmm<<<dim3(4, 4, 2), 256, 0, stream>>>(slabF, slabF, slabF + 65536, SS, SS, SS, 1);
  k_powmm<<<dim3(4, 4, 4), 256, 0, stream>>>(slabF, slabF + 65536, slabF + 2 * 65536, SS, SS, SS, 2);
  k_powmm<<<dim3(4, 4, 8), 256, 0, stream>>>(slabF, slabF + 3 * 65536, slabF + 4 * 65536, SS, SS, SS, 4);
  k_powmm<<<dim3(4, 4, 16), 256, 0, stream>>>(slabF, slabF + 7 * 65536, slabF + 8 * 65536, SS, SS, SS, 8);
  k_powmm<<<dim3(4, 4, 2), 256, 0, stream>>>(slabF + 15 * 65536, slabF + 15 * 65536, tA, SS, SS, 65536, 1); // ^32
  k_powmm<<<dim3(4, 4, 2), 256, 0, stream>>>(tA, tA, tB, 65536, 65536, 65536, 1);   // ^64
  k_powmm<<<dim3(4, 4, 2), 256, 0, stream>>>(tB, tB, tA, 65536, 65536, 65536, 1);   // ^128
  k_powmm<<<dim3(4, 4, 2), 256, 0, stream>>>(tA, tA, P256F, 65536, 65536, 65536, 1);// ^256
  k_castT<<<dim3(16, 37), 256, 0, stream>>>(slabF, Wi1, m0W, m1W, slabT, WtT);
  hipMemsetAsync(stats, 0, 8 * 512 * sizeof(float), stream);

  for (int blk = 0; blk < 4; ++blk) {
    const int pi = blk ? 1 : 0;
    const float* P16f = slabF + pi * SS + 15 * 65536;
    const float* P256f = P256F + pi * 65536;
    const ushort_t* slabTp = slabT + pi * SS;
    const float* mb = pi ? m1b : m0b;
    const float* msc = pi ? m1s : m0s;
    const float* mbi = pi ? m1bi : m0bi;

    if (blk == 0) {
      // embedding fused into scan epilogue
      k_scan_mfma<1><<<64, 256, 0, stream>>>(nullptr, x, Wi0, bi0, slabTp, HA, e1);
    } else {
      // u-drive: h2 = gelu(bn(y1;prev-l1)) + h1 computed in staging; u = h2@Wi1+bi1
      const int ppi = (blk - 1) ? 1 : 0;
      const float* pst = stats + ((blk - 1) * 2 + 1) * 512;
      const float* psc = (ppi ? m1s : m0s) + 256;
      const float* pbi = (ppi ? m1bi : m0bi) + 256;
      k_gemm<0, 1><<<dim3(128, 2), 256, 0, stream>>>(Y1, HB, pst, psc, pbi,
                                                     WtT, bi1, U, nullptr, nullptr);
      k_scan_mfma<0><<<64, 256, 0, stream>>>(U, nullptr, nullptr, nullptr, slabTp, HA, e1);
    }

    // hierarchical true-init computation (exact f32)
    k_scan<<<32, 512, 0, stream>>>(e1, P16f, nullptr, nullptr, e2, 16, 1);
    k_scan<<<4, 512, 0, stream>>>(e2, P256f, nullptr, t2, nullptr, 8, 1);
    k_scan<<<32, 512, 0, stream>>>(e1, P16f, t2, ee1, nullptr, 16, 8);
    // h += Init @ Wh^{j+1}
    k_corr<<<dim3(8, 2, 16), 256, 0, stream>>>(ee1, slabTp, HA);

    // MLP layer 0: y0 = h@W0+b0 (+stats)
    k_gemm<1, 0><<<dim3(128, 2), 256, 0, stream>>>(HA, nullptr, nullptr, nullptr, nullptr,
                                                   WtT + (1 + pi * 2) * 65536, mb,
                                                   Y0, stats + (blk * 2) * 512, nullptr);
    // MLP layer 1: staging computes h1 = gelu(bn(y0))+h (writeback -> HB); y1 = h1@W1+b1
    k_gemm<1, 1><<<dim3(128, 2), 256, 0, stream>>>(Y0, HA, stats + (blk * 2) * 512,
                                                   msc, mbi,
                                                   WtT + (1 + pi * 2 + 1) * 65536, mb + 256,
                                                   Y1, stats + (blk * 2 + 1) * 512, HB);
  }

  // logits with fused h_final = gelu(bn(y1;st7))+h1
  k_logits<<<256, 256, 0, stream>>>(Y1, HB, stats + 7 * 512, m1s + 256, m1bi + 256,
                                    Wr, br, (float*)d_out);
}